// Round 8
// baseline (384.616 us; speedup 1.0000x reference)
//
#include <hip/hip_runtime.h>

#define BATCH 8
#define HH 2048
#define WW 2048
#define NPIX (HH*WW)
#define TOPK 8192
#define NB 4096
#define PEAK_CAP 196608
#define CHUNK 8192
#define NCHUNK 24
#define FCHUNK 8192
#define LBINS 512
#define LO_BIN (NB - LBINS)
#define CAND_CAP 16384

// workspace byte offsets
#define OFF_PEAKS  0ull
#define OFF_CANDS  (OFF_PEAKS + (size_t)BATCH*PEAK_CAP*8ull)     // 12.6 MB
#define OFF_HIST   (OFF_CANDS + (size_t)BATCH*CAND_CAP*8ull)     // +1 MB
#define OFF_SA     (OFF_HIST  + (size_t)BATCH*NB*4ull)
#define OFF_FILL   (OFF_SA    + (size_t)BATCH*NB*4ull)
#define OFF_PCOUNT (OFF_FILL  + (size_t)BATCH*NB*4ull)
#define OFF_NCAND  (OFF_PCOUNT + 64ull)
#define OFF_BSTAR  (OFF_NCAND + 64ull)
#define OFF_END    (OFF_PCOUNT + 192ull)
#define OFF_PART   (OFF_PCOUNT + 256ull)
// partials: BATCH * NCHUNK * (NB/2) u32 = 1.5 MB ; total ws ~15.5 MB

__device__ __forceinline__ int bucket_of(float v) {
    int bk = (int)(v * 4096.0f);
    if (bk > NB - 1) bk = NB - 1;
    if (bk < 0) bk = 0;
    return bk;
}

// ---------------- K1: NMS, register-direct, full load MLP ----------------
// Block 256 as 16x16; thread: 4 cols x 4 rows. R7: ALL 24 float4 loads hoisted
// into L[8][3] and issued back-to-back (R6's VGPR=48 build serialized them into
// ~6-reg batches, eating full memory latency each). launch_bounds(256,3)
// raises the VGPR cap to ~168 so the hoist survives. grid (32, 32, 8).
__global__ __launch_bounds__(256, 3) void k_nms(
    const float* __restrict__ scores,
    unsigned long long* __restrict__ peaks,
    unsigned int* __restrict__ pcount)
{
    const int b = blockIdx.z;
    const int tx = threadIdx.x & 15;
    const int ty = threadIdx.x >> 4;
    const int x = blockIdx.x * 64 + tx * 4;
    const int y = blockIdx.y * 64 + ty * 4;
    const float* img = scores + (size_t)b * NPIX;
    const float4* imgq = (const float4*)img;

    __shared__ unsigned long long lbuf[512];
    __shared__ unsigned int lcnt;
    __shared__ unsigned int lbase;
    if (threadIdx.x == 0) lcnt = 0;
    __syncthreads();

    const int q = x >> 2;
    const int qm = (q > 0) ? q - 1 : 0;
    const int qp = (q < WW / 4 - 1) ? q + 1 : WW / 4 - 1;

    // ---- all loads first: 24 global_load_dwordx4 in flight ----
    float4 L[8][3];
#pragma unroll
    for (int j = 0; j < 8; ++j) {
        int gy = y - 2 + j;
        gy = gy < 0 ? 0 : (gy > HH - 1 ? HH - 1 : gy);
        const float4* rowq = imgq + (size_t)gy * (WW / 4);
        L[j][0] = rowq[qm];
        L[j][1] = rowq[q];
        L[j][2] = rowq[qp];
    }

    // ---- compute ----
    float hm[8][4];
    float c4[4][4];
#pragma unroll
    for (int j = 0; j < 8; ++j) {
        const float v[12] = {L[j][0].x, L[j][0].y, L[j][0].z, L[j][0].w,
                             L[j][1].x, L[j][1].y, L[j][1].z, L[j][1].w,
                             L[j][2].x, L[j][2].y, L[j][2].z, L[j][2].w};
        float aa[8];
#pragma unroll
        for (int k = 0; k < 8; ++k) aa[k] = fmaxf(v[k + 2], v[k + 3]);
#pragma unroll
        for (int i = 0; i < 4; ++i)
            hm[j][i] = fmaxf(fmaxf(aa[i], aa[i + 2]), v[i + 6]);
        if (j >= 2 && j <= 5) {
#pragma unroll
            for (int i = 0; i < 4; ++i) c4[j - 2][i] = v[i + 4];
        }
    }

#pragma unroll
    for (int r = 0; r < 4; ++r) {
        const int oy = y + r;
        const bool yok = (oy >= 2) && (oy <= HH - 3);
#pragma unroll
        for (int i = 0; i < 4; ++i) {
            const float vm = fmaxf(fmaxf(fmaxf(hm[r][i], hm[r + 1][i]),
                                         fmaxf(hm[r + 2][i], hm[r + 3][i])),
                                   hm[r + 4][i]);
            const float cv = c4[r][i];
            const int col = x + i;
            if (yok && col >= 2 && col <= WW - 3 && cv == vm) {
                unsigned int pos = atomicAdd(&lcnt, 1u);
                if (pos < 512u) {
                    unsigned int idx = (unsigned int)(oy * WW + col);
                    lbuf[pos] = ((unsigned long long)__float_as_uint(cv) << 32) |
                                (unsigned long long)(~idx);
                }
            }
        }
    }
    __syncthreads();

    unsigned int cnt = lcnt;
    if (cnt > 512u) cnt = 512u;
    if (threadIdx.x == 0) lbase = atomicAdd(&pcount[b], cnt);
    __syncthreads();
    const unsigned int gbase = lbase;
    for (unsigned int s = threadIdx.x; s < cnt; s += 256) {
        unsigned int gpos = gbase + s;
        if (gpos < PEAK_CAP) peaks[(size_t)b * PEAK_CAP + gpos] = lbuf[s];
    }
}

// ---------------- K1b: per-chunk LDS-private histogram ----------------
// grid (NCHUNK=24, BATCH), block 256, 8 KB LDS. R7: 4x more blocks (was 48).
__global__ __launch_bounds__(256) void k_hist(
    const unsigned long long* __restrict__ peaks,
    const unsigned int* __restrict__ pcount,
    unsigned int* __restrict__ partials)
{
    const int b = blockIdx.y;
    const int blk = blockIdx.x;
    unsigned int n = pcount[b];
    if (n > PEAK_CAP) n = PEAK_CAP;
    const unsigned int base = blk * CHUNK;

    __shared__ unsigned int h[NB / 2];   // 8 KB packed u16 pairs
    for (int w = threadIdx.x; w < NB / 2; w += 256) h[w] = 0u;
    __syncthreads();

    if (base < n) {
        const unsigned int end = (base + CHUNK < n) ? base + CHUNK : n;
        for (unsigned int i = base + threadIdx.x; i < end; i += 256) {
            unsigned long long key = peaks[(size_t)b * PEAK_CAP + i];
            float v = __uint_as_float((unsigned int)(key >> 32));
            int bk = bucket_of(v);
            atomicAdd(&h[bk >> 1], (bk & 1) ? 0x10000u : 1u);
        }
    }
    __syncthreads();

    unsigned int* dst = partials + ((size_t)(b * NCHUNK + blk)) * (NB / 2);
    for (int w = threadIdx.x; w < NB / 2; w += 256) dst[w] = h[w];
}

// ---------------- K2: merge partials + suffix scan, find B* ----------------
// grid: (8), block 256. NB=4096: merge is 2048 words x 24 chunks, coalesced.
__global__ __launch_bounds__(256) void k_scan(
    const unsigned int* __restrict__ partials,
    const unsigned int* __restrict__ pcount,
    unsigned int* __restrict__ hist,
    unsigned int* __restrict__ SA,
    unsigned int* __restrict__ ncand,
    unsigned int* __restrict__ bstar)
{
    const int b = blockIdx.x;
    unsigned int n = pcount[b];
    if (n > PEAK_CAP) n = PEAK_CAP;
    const int nblk = (int)((n + CHUNK - 1) / CHUNK);
    unsigned int* sab = SA + b * NB;
    const int t = threadIdx.x;

    __shared__ unsigned int h[NB / 2];   // packed lo | hi<<16, 8 KB
    __shared__ unsigned int ps[256];
    __shared__ int bmax;

    for (int w = t; w < NB / 2; w += 256) {
        unsigned int lo = 0, hi = 0;
        for (int k = 0; k < nblk; ++k) {
            unsigned int p = partials[(size_t)(b * NCHUNK + k) * (NB / 2) + w];
            lo += p & 0xFFFFu;
            hi += p >> 16;
        }
        h[w] = lo | (hi << 16);
        ((uint2*)hist)[(size_t)b * (NB / 2) + w] = make_uint2(lo, hi);
    }
    __syncthreads();

    // per-thread 16-bin total (8 packed words)
    unsigned int sum = 0;
    for (int k = 0; k < 8; ++k) {
        const unsigned int p = h[t * 8 + k];
        sum += (p & 0xFFFFu) + (p >> 16);
    }
    ps[t] = sum;
    __syncthreads();
    for (int off = 1; off < 256; off <<= 1) {
        unsigned int v = (t + off < 256) ? ps[t + off] : 0u;
        __syncthreads();
        ps[t] += v;
        __syncthreads();
    }
    unsigned int run = ps[t] - sum;  // strictly above this thread's bins
    int bst_local = -1;
    for (int i = 15; i >= 0; --i) {
        const int bin = t * 16 + i;
        const unsigned int w = h[t * 8 + (i >> 1)];
        const unsigned int hv = (i & 1) ? (w >> 16) : (w & 0xFFFFu);
        sab[bin] = run;
        if (run + hv >= TOPK && bst_local < 0) bst_local = bin;
        run += hv;
    }
    if (t == 0) bmax = -1;
    __syncthreads();
    if (bst_local >= 0) atomicMax(&bmax, bst_local);
    __syncthreads();
    if (t == 0) {
        const int Bs = bmax < 0 ? 0 : bmax;
        bstar[b] = (unsigned int)Bs;
        const unsigned int w = h[Bs >> 1];
        const unsigned int hv = (Bs & 1) ? (w >> 16) : (w & 0xFFFFu);
        unsigned int nc = sab[Bs] + hv;
        if (nc > CAND_CAP) nc = CAND_CAP;
        ncand[b] = nc;
    }
}

// ---------------- K3: filter -> bucket-grouped cands, aggregated atomics ----------------
// grid (24, 8), block 256. Two-pass per 8192-key chunk; one global atomic per
// (block,bin) for the top LBINS bins; fallback for cold bins.
__global__ __launch_bounds__(256) void k_filter(
    const unsigned long long* __restrict__ peaks,
    const unsigned int* __restrict__ pcount,
    const unsigned int* __restrict__ bstar,
    const unsigned int* __restrict__ SA,
    unsigned int* __restrict__ fill,
    unsigned long long* __restrict__ cands)
{
    const int b = blockIdx.y;
    unsigned int n = pcount[b];
    if (n > PEAK_CAP) n = PEAK_CAP;
    const unsigned int base = blockIdx.x * FCHUNK;
    if (base >= n) return;
    const unsigned int end = (base + FCHUNK < n) ? base + FCHUNK : n;
    const unsigned int bs = bstar[b];
    const unsigned long long* pb = peaks + (size_t)b * PEAK_CAP;
    unsigned long long* cb = cands + (size_t)b * CAND_CAP;

    __shared__ unsigned int cnt[LBINS];
    __shared__ unsigned int off[LBINS];
    for (int j = threadIdx.x; j < LBINS; j += 256) { cnt[j] = 0u; off[j] = 0u; }
    __syncthreads();

    for (unsigned int i = base + threadIdx.x; i < end; i += 256) {
        const unsigned long long key = pb[i];
        const float v = __uint_as_float((unsigned int)(key >> 32));
        const int bk = bucket_of(v);
        if ((unsigned int)bk < bs) continue;
        if (bk >= LO_BIN) {
            atomicAdd(&cnt[bk - LO_BIN], 1u);
        } else {
            unsigned int pos = SA[b * NB + bk] + atomicAdd(&fill[b * NB + bk], 1u);
            if (pos < CAND_CAP) cb[pos] = key;
        }
    }
    __syncthreads();

    for (int j = threadIdx.x; j < LBINS; j += 256) {
        const unsigned int c = cnt[j];
        if (c) cnt[j] = atomicAdd(&fill[b * NB + LO_BIN + j], c);
    }
    __syncthreads();

    for (unsigned int i = base + threadIdx.x; i < end; i += 256) {
        const unsigned long long key = pb[i];
        const float v = __uint_as_float((unsigned int)(key >> 32));
        const int bk = bucket_of(v);
        if ((unsigned int)bk < bs || bk < LO_BIN) continue;
        const unsigned int l = atomicAdd(&off[bk - LO_BIN], 1u);
        const unsigned int pos = SA[b * NB + bk] + cnt[bk - LO_BIN] + l;
        if (pos < CAND_CAP) cb[pos] = key;
    }
}

// ---------------- K4: exact rank within bucket + per-keypoint outputs ----------------
// grid: (64, 8), block 256
__global__ __launch_bounds__(256) void k_out(
    const float* __restrict__ scores,
    const unsigned long long* __restrict__ cands,
    const unsigned int* __restrict__ ncand,
    const unsigned int* __restrict__ SA,
    const unsigned int* __restrict__ hist,
    float* __restrict__ out)
{
    const int b = blockIdx.y;
    unsigned int n = ncand[b];
    if (n > CAND_CAP) n = CAND_CAP;
    const int base = blockIdx.x * 256;
    const unsigned long long* cb = cands + (size_t)b * CAND_CAP;

    __shared__ unsigned long long seg[1024];  // window [base-384, base+640)
    for (int t = threadIdx.x; t < 1024; t += 256) {
        int gi = base - 384 + t;
        unsigned long long v = 0ull;
        if (gi >= 0 && gi < (int)n) v = cb[gi];
        seg[t] = v;
    }
    __syncthreads();

    unsigned int ci = base + threadIdx.x;
    if (ci >= n) return;

    const unsigned long long key = cb[ci];
    float v = __uint_as_float((unsigned int)(key >> 32));
    const int bk = bucket_of(v);
    const unsigned int seg0 = SA[b * NB + bk];
    const unsigned int len = hist[b * NB + bk];

    unsigned int r = 0;
    if ((int)seg0 >= base - 384 && (int)(seg0 + len) <= base + 640) {
        const int s0 = (int)seg0 - (base - 384);
        for (unsigned int j = 0; j < len; ++j)
            r += (seg[s0 + j] > key) ? 1u : 0u;
    } else {
#pragma unroll 4
        for (unsigned int j = 0; j < len; ++j)
            r += (cb[seg0 + j] > key) ? 1u : 0u;
    }
    const unsigned int rank = seg0 + r;
    if (rank >= TOPK) return;

    const unsigned int idx = ~((unsigned int)(key & 0xFFFFFFFFull));
    const int ky = (int)(idx >> 11);
    const int kx = (int)(idx & (WW - 1));
    const float* img = scores + (size_t)b * NPIX;

    float patch[25];
#pragma unroll
    for (int dy = 0; dy < 5; ++dy) {
#pragma unroll
        for (int dx = 0; dx < 5; ++dx) {
            patch[dy * 5 + dx] = img[(size_t)(ky + dy - 2) * WW + (kx + dx - 2)];
        }
    }
    float mx = patch[0];
#pragma unroll
    for (int p = 1; p < 25; ++p) mx = fmaxf(mx, patch[p]);

    float e[25];
    float s = 0.0f, sx = 0.0f, sy = 0.0f;
#pragma unroll
    for (int p = 0; p < 25; ++p) {
        float ex = expf((patch[p] - mx) * 10.0f);
        e[p] = ex;
        s += ex;
        sx += ex * (float)(p % 5 - 2);
        sy += ex * (float)(p / 5 - 2);
    }
    const float xx = sx / s;
    const float yy = sy / s;

    float dsum = 0.0f;
#pragma unroll
    for (int p = 0; p < 25; ++p) {
        float ddx = ((float)(p % 5 - 2) - xx) * 0.5f;
        float ddy = ((float)(p / 5 - 2) - yy) * 0.5f;
        dsum += e[p] * (ddx * ddx + ddy * ddy);
    }
    const float disp = dsum / s;

    const float kxy_x = ((float)kx + xx) / (float)(WW - 1) * 2.0f - 1.0f;
    const float kxy_y = ((float)ky + yy) / (float)(HH - 1) * 2.0f - 1.0f;

    const float px = (kxy_x + 1.0f) * 0.5f * (float)(WW - 1);
    const float py = (kxy_y + 1.0f) * 0.5f * (float)(HH - 1);
    int x0 = (int)floorf(px); x0 = x0 < 0 ? 0 : (x0 > WW - 1 ? WW - 1 : x0);
    int y0 = (int)floorf(py); y0 = y0 < 0 ? 0 : (y0 > HH - 1 ? HH - 1 : y0);
    int x1 = x0 + 1 > WW - 1 ? WW - 1 : x0 + 1;
    int y1 = y0 + 1 > HH - 1 ? HH - 1 : y0 + 1;
    const float wx = px - (float)x0;
    const float wy = py - (float)y0;
    const float v00 = img[(size_t)y0 * WW + x0];
    const float v01 = img[(size_t)y0 * WW + x1];
    const float v10 = img[(size_t)y1 * WW + x0];
    const float v11 = img[(size_t)y1 * WW + x1];
    const float ksc = v00 * (1.0f - wx) * (1.0f - wy) + v01 * wx * (1.0f - wy)
                    + v10 * (1.0f - wx) * wy + v11 * wx * wy;

    const size_t ok = (size_t)b * TOPK + rank;
    out[2 * ok]     = kxy_x;
    out[2 * ok + 1] = kxy_y;
    out[(size_t)BATCH * TOPK * 2 + ok] = ksc;
    out[(size_t)BATCH * TOPK * 3 + ok] = disp;
}

extern "C" void kernel_launch(void* const* d_in, const int* in_sizes, int n_in,
                              void* d_out, int out_size, void* d_ws, size_t ws_size,
                              hipStream_t stream) {
    const float* scores = (const float*)d_in[0];
    float* out = (float*)d_out;
    char* ws = (char*)d_ws;

    unsigned long long* peaks = (unsigned long long*)(ws + OFF_PEAKS);
    unsigned long long* cands = (unsigned long long*)(ws + OFF_CANDS);
    unsigned int* hist   = (unsigned int*)(ws + OFF_HIST);
    unsigned int* SA     = (unsigned int*)(ws + OFF_SA);
    unsigned int* fill   = (unsigned int*)(ws + OFF_FILL);
    unsigned int* pcount = (unsigned int*)(ws + OFF_PCOUNT);
    unsigned int* ncand  = (unsigned int*)(ws + OFF_NCAND);
    unsigned int* bstar  = (unsigned int*)(ws + OFF_BSTAR);
    unsigned int* part   = (unsigned int*)(ws + OFF_PART);

    // zero fill + counters only (hist/SA are fully overwritten by k_scan)
    hipMemsetAsync(ws + OFF_FILL, 0, (size_t)(OFF_END - OFF_FILL), stream);

    k_nms<<<dim3(WW / 64, HH / 64, BATCH), 256, 0, stream>>>(scores, peaks, pcount);
    k_hist<<<dim3(NCHUNK, BATCH), 256, 0, stream>>>(peaks, pcount, part);
    k_scan<<<dim3(BATCH), 256, 0, stream>>>(part, pcount, hist, SA, ncand, bstar);
    k_filter<<<dim3(PEAK_CAP / FCHUNK, BATCH), 256, 0, stream>>>(peaks, pcount, bstar, SA, fill, cands);
    k_out<<<dim3(CAND_CAP / 256, BATCH), 256, 0, stream>>>(scores, cands, ncand, SA, hist, out);
}